// Round 14
// baseline (26.685 us; speedup 1.0000x reference)
//
#include <hip/hip_runtime.h>
#include <stdint.h>

constexpr int BATCH = 16384;
constexpr int A     = 50;
constexpr int NN    = 51;   // A + 1
constexpr int MAXR  = 16;
constexpr int EPB   = 16;   // elements per block
constexpr int EPWB  = 4;    // elements per wave in phase B
constexpr int WPB   = 4;    // waves per block (256 threads)
constexpr int RW    = MAXR * A;      // 800 words per element's rings region
constexpr int RW4   = RW / 4;        // 200 int4

// Decoupled fused kernel: block = 16 elements, 4 waves.
//   stage (all) -> barrier -> phase A (wave 0, quad-split EPW=16)
//   -> barrier -> phase B (4 waves x 4 elements): ring rows scattered into a
//   per-wave LDS buffer (pre-init -1, store-and-forget ds_writes), then dumped
//   once with coalesced int4 stores. Every output byte written exactly once.
__global__ __launch_bounds__(WPB * 64, 4)
void fused_kernel(const int* __restrict__ edge, int* __restrict__ out)
{
    const int tid   = threadIdx.x;
    const int bbase = blockIdx.x * EPB;   // block's first element

    __shared__ uint32_t eds [EPB][NN];    // packed me[e][n+1][0..3]
    __shared__ uint16_t comb[EPB][128];   // [0..63]=Tree, [64..127]=ring slots
    __shared__ int      rbuf[WPB][RW];    // per-wave ring-row compose buffer

    {   // zero comb: 16*128*2B = 4096B = 256 uint4 (one per thread)
        ((uint4*)&comb[0][0])[tid] = make_uint4(0, 0, 0, 0);
    }
    {   // stage + pack block's edges: 16 elements x 50 int4, coalesced
        const int4* e4 = (const int4*)edge + (size_t)bbase * A;
        #pragma unroll
        for (int k = 0; k < 4; ++k) {
            const int gi = k * 256 + tid;
            if (gi < EPB * A) {
                const int4 v = e4[gi];
                const int el = gi / A, n = gi - A * el;
                eds[el][n] = (uint32_t)(v.x + 1) | ((uint32_t)(v.y + 1) << 8)
                           | ((uint32_t)(v.z + 1) << 16) | ((uint32_t)(v.w + 1) << 24);
            }
        }
    }
    __syncthreads();

    if (tid < 64) {
        // ---------------- phase A: wave 0, quad-split, 16 elements ----------------
        const int e = tid >> 2;    // element within block
        const int d = tid & 3;     // edge index this lane handles

        uint64_t L = (((uint64_t)1 << NN) - 1) & ~(uint64_t)3;  // lnf: 0,1 found
        uint64_t V = (((uint64_t)1 << NN) - 1) & ~(uint64_t)1;  // nnv: 0 visited
        uint64_t M = 2;               // found & not visited = {1}
        int visiting = 1, nr = 0;
        uint32_t w = eds[e][0];       // prefetched row of node 1

        #pragma unroll 1
        for (int it = 0; it < A; ++it) {
            const int n0 = w & 0xff, n1 = (w >> 8) & 0xff, n2 = (w >> 16) & 0xff, n3 = w >> 24;
            const uint64_t bu = ((uint64_t)1 << n0) | ((uint64_t)1 << n1)
                              | ((uint64_t)1 << n2) | ((uint64_t)1 << n3);
            const int myn = (w >> (8 * d)) & 0xff;
            const uint64_t bm = (uint64_t)1 << myn;
            // --- next-visit precompute + prefetch (overlaps bookkeeping) ---
            const uint64_t visbit = (uint64_t)1 << visiting;
            const uint64_t Mn = (M | (V & bu)) & ~visbit;   // next found&!visited set
            const bool dn = (Mn == 0);
            const uint64_t Msafe = dn ? (uint64_t)2 : Mn;
            const int nv = (int)__builtin_ctzll(Msafe);     // next visiting (dummy 1 if done)
            const uint32_t wn = eds[e][nv - 1];             // prefetch next edge row
            // --- bookkeeping with OLD L,V ---
            const bool dup = ((d > 0) & (myn == n0)) | ((d > 1) & (myn == n1)) | ((d > 2) & (myn == n2));
            const bool fa  = ((L & bm) == 0) | dup;         // found at my edge's turn
            const bool cf  = fa & ((V & bm) != 0) & (myn != 0);   // cycle edge
            const uint64_t Bc = __ballot(cf);               // all 4 lanes of each quad
            const uint32_t qb = (uint32_t)(Bc >> (tid & 60)) & 0xfu;  // my quad's bits
            const int slot = nr + __builtin_popcount(qb & ((1u << d) - 1));
            nr += __builtin_popcount(qb);
            // exec-guarded stores: few active lanes
            if (!fa) comb[e][myn] = (uint16_t)visiting;     // Tree set-once
            if (cf && slot < NN)
                comb[e][64 + slot] = (uint16_t)(visiting | (myn << 8));  // ring push
            L &= ~bu;
            V &= ~visbit;
            M = Mn; visiting = nv;
            w = dn ? 0u : wn;   // done lanes idle harmlessly
            if (__ballot(!dn) == 0) break;
        }
    }
    __syncthreads();

    // ---------------- phase B: 4 waves x 4 elements ----------------
    const int lane  = tid & 63;
    const int wid   = tid >> 6;
    const int ebase = wid * EPWB;             // this wave's first element in block
    const int gbase = bbase + ebase;          // global element index

    int*  otree = out;                                   // (B,51)
    int2* oridx = (int2*)(out + (size_t)BATCH * NN);     // (B,51) of int2

    uint64_t MkE[EPWB];
    int gE[EPWB], r01E[EPWB];
    #pragma unroll
    for (int j = 0; j < EPWB; ++j) {
        const int ew = ebase + j;
        const int b  = gbase + j;
        const int f = (lane < NN) ? (int)comb[ew][lane] : 0;
        const uint32_t pv = (lane < NN) ? (uint32_t)comb[ew][64 + lane] : 0;
        MkE[j] = ((uint64_t)1 << lane) | ((uint64_t)1 << f);
        gE[j]  = f;
        r01E[j] = (int)pv;                               // slot lane: r0 | r1<<8
        if (lane < NN) {
            otree[(size_t)b * NN + lane] = f;
            oridx[(size_t)b * NN + lane] = make_int2((int)(pv & 0xff), (int)(pv >> 8));
        }
    }
    // ancestor-mask doubling: issue all bpermutes of a step, then combine
    #pragma unroll
    for (int j6 = 0; j6 < 6; ++j6) {
        int lo4[EPWB], hi4[EPWB], gg4[EPWB];
        #pragma unroll
        for (int j = 0; j < EPWB; ++j) {
            const int ad = gE[j] << 2;
            lo4[j] = __builtin_amdgcn_ds_bpermute(ad, (int)(uint32_t)MkE[j]);
            hi4[j] = __builtin_amdgcn_ds_bpermute(ad, (int)(MkE[j] >> 32));
            gg4[j] = (j6 < 5) ? __builtin_amdgcn_ds_bpermute(ad, gE[j]) : gE[j];
        }
        #pragma unroll
        for (int j = 0; j < EPWB; ++j) {
            MkE[j] |= ((uint64_t)(uint32_t)hi4[j] << 32) | (uint32_t)lo4[j];
            gE[j]   = gg4[j];
        }
    }
    // slot prep: issue all 16 bpermutes, then combine
    int depE[EPWB], nactE[EPWB], packE[EPWB];
    int s0loE[EPWB], s0hiE[EPWB], s1loE[EPWB], s1hiE[EPWB];
    {
        int t0l[EPWB], t0h[EPWB], t1l[EPWB], t1h[EPWB];
        #pragma unroll
        for (int j = 0; j < EPWB; ++j) {
            const int Mlo = (int)(uint32_t)MkE[j], Mhi = (int)(MkE[j] >> 32);
            const int a0 = (r01E[j] & 0xff) << 2, a1 = ((r01E[j] >> 8) & 0xff) << 2;
            t0l[j] = __builtin_amdgcn_ds_bpermute(a0, Mlo);
            t0h[j] = __builtin_amdgcn_ds_bpermute(a0, Mhi);
            t1l[j] = __builtin_amdgcn_ds_bpermute(a1, Mlo);
            t1h[j] = __builtin_amdgcn_ds_bpermute(a1, Mhi);
        }
        #pragma unroll
        for (int j = 0; j < EPWB; ++j) {
            const uint64_t set0 = ((uint64_t)(uint32_t)t0h[j] << 32) | (uint32_t)t0l[j];
            const uint64_t set1 = ((uint64_t)(uint32_t)t1h[j] << 32) | (uint32_t)t1l[j];
            depE[j] = __builtin_popcountll(MkE[j]) - 1;
            const int dm  = __builtin_popcountll(set0 & set1) - 1;  // LCA depth
            const int ds0 = __builtin_popcountll(set0) - 1;
            const int ds1 = __builtin_popcountll(set1) - 1;
            const int r0  = r01E[j] & 0xff;
            s0loE[j] = (int)(uint32_t)set0;  s0hiE[j] = (int)(set0 >> 32);
            s1loE[j] = (int)(uint32_t)set1;  s1hiE[j] = (int)(set1 >> 32);
            packE[j] = dm | (ds0 << 8) | (ds1 << 16) | (r0 << 24);
            nactE[j] = __popcll(__ballot((lane < MAXR) && (r0 != 0)));
        }
    }

    // row emission via LDS scatter buffer, one element at a time
    int4* rb4 = (int4*)&rbuf[wid][0];
    #pragma unroll 1
    for (int j = 0; j < EPWB; ++j) {
        const int b = gbase + j;
        const int nact = nactE[j];
        const int dep  = depE[j];

        // init buffer to -1 (200 int4)
        const int4 m1 = make_int4(-1, -1, -1, -1);
        #pragma unroll
        for (int k = 0; k < 4; ++k) {
            const int f = k * 64 + lane;
            if (f < RW4) rb4[f] = m1;
        }
        // scatter active rows (store-and-forget, no result dependency)
        for (int i = 0; i < nact; ++i) {
            const uint64_t s0 = ((uint64_t)(uint32_t)__builtin_amdgcn_readlane(s0hiE[j], i) << 32)
                              |  (uint32_t)__builtin_amdgcn_readlane(s0loE[j], i);
            const uint64_t s1 = ((uint64_t)(uint32_t)__builtin_amdgcn_readlane(s1hiE[j], i) << 32)
                              |  (uint32_t)__builtin_amdgcn_readlane(s1loE[j], i);
            const int pk = __builtin_amdgcn_readlane(packE[j], i);
            const int dm = pk & 0xff, ds0 = (pk >> 8) & 0xff, ds1 = (pk >> 16) & 0xff;
            const int s0v = (pk >> 24) & 0xff;
            const int ta = ds1 - dm;
            const bool on1 = ((s1 >> lane) & 1) && (dep >= dm);  // s1-chain node
            const bool on0 = ((s0 >> lane) & 1) && (dep >  dm);  // s0-chain below LCA
            const int pos = on1 ? (ds1 - dep) : on0 ? (ta + 1 + ds0 - dep) : 99;
            if (pos < A) rbuf[wid][i * A + pos] = lane - 1;       // node -> its slot
            if (lane == 63 && ta + 1 < A)
                rbuf[wid][i * A + ta + 1] = s0v - 1;              // s0 slot (agrees where it collides)
        }
        // dump element's whole rings region once, coalesced int4
        int4* og = (int4*)(out + (size_t)BATCH * NN * 3 + (size_t)b * RW);
        #pragma unroll
        for (int k = 0; k < 4; ++k) {
            const int f = k * 64 + lane;
            if (f < RW4) og[f] = rb4[f];
        }
    }
}

extern "C" void kernel_launch(void* const* d_in, const int* in_sizes, int n_in,
                              void* d_out, int out_size, void* d_ws, size_t ws_size,
                              hipStream_t stream) {
    const int* edge = (const int*)d_in[0];
    int* out = (int*)d_out;
    hipLaunchKernelGGL(fused_kernel, dim3(BATCH / EPB), dim3(WPB * 64), 0, stream,
                       edge, out);
}

// Round 15
// 24.438 us; speedup vs baseline: 1.0920x; 1.0920x over previous
//
#include <hip/hip_runtime.h>
#include <stdint.h>

constexpr int BATCH = 16384;
constexpr int A     = 50;
constexpr int NN    = 51;   // A + 1
constexpr int MAXR  = 16;
constexpr int EPB   = 16;   // elements per block
constexpr int EPWB  = 2;    // elements per wave in phase B
constexpr int WPB   = 8;    // waves per block (512 threads)

// Phase-B row prep: everything up to (but not including) the ds_permute.
// pk = dm | ds0<<8 | ds1<<16 | s0v<<24 (one readlane for all four scalars).
__device__ __forceinline__ void prep_row(int lane, int dep,
    int s0lo, int s0hi, int s1lo, int s1hi, int pack, int i,
    int& pos, int& ta, int& tua, int& s0v)
{
    const uint64_t s0 = ((uint64_t)(uint32_t)__builtin_amdgcn_readlane(s0hi, i) << 32)
                      |  (uint32_t)__builtin_amdgcn_readlane(s0lo, i);
    const uint64_t s1 = ((uint64_t)(uint32_t)__builtin_amdgcn_readlane(s1hi, i) << 32)
                      |  (uint32_t)__builtin_amdgcn_readlane(s1lo, i);
    const int pk = __builtin_amdgcn_readlane(pack, i);
    const int dm = pk & 0xff, ds0 = (pk >> 8) & 0xff, ds1 = (pk >> 16) & 0xff;
    s0v = (pk >> 24) & 0xff;
    ta  = ds1 - dm;
    tua = ta + ds0 - dm;
    const bool on1 = ((s1 >> lane) & 1) && (dep >= dm);
    const bool on0 = ((s0 >> lane) & 1) && (dep >  dm);
    int p = on1 ? (ds1 - dep) : on0 ? (ta + 1 + ds0 - dep) : 63;
    pos = p < 63 ? p : 63;
}

// Decoupled fused kernel: block = 16 elements, 8 waves (512 threads).
//   stage (all) -> barrier -> { wave 0: phase A | waves 1-7: -1 fill of the
//   block's whole rings region } -> barrier -> phase B (8 waves x 2 elements,
//   active rows only). 8 waves/SIMD for latency hiding (VGPR capped at 64).
__global__ __launch_bounds__(WPB * 64, 8)
void fused_kernel(const int* __restrict__ edge, int* __restrict__ out)
{
    const int tid   = threadIdx.x;
    const int bbase = blockIdx.x * EPB;   // block's first element

    __shared__ uint32_t eds [EPB][NN];    // packed me[e][n+1][0..3]
    __shared__ uint16_t comb[EPB][128];   // [0..63]=Tree, [64..127]=ring slots

    {   // zero comb: 16*128*2B = 4096B = 256 uint4
        if (tid < 256) ((uint4*)&comb[0][0])[tid] = make_uint4(0, 0, 0, 0);
    }
    {   // stage + pack block's edges: 16 elements x 50 int4, coalesced
        const int4* e4 = (const int4*)edge + (size_t)bbase * A;
        #pragma unroll
        for (int k = 0; k < 2; ++k) {
            const int gi = k * 512 + tid;
            if (gi < EPB * A) {
                const int4 v = e4[gi];
                const int el = gi / A, n = gi - A * el;
                eds[el][n] = (uint32_t)(v.x + 1) | ((uint32_t)(v.y + 1) << 8)
                           | ((uint32_t)(v.z + 1) << 16) | ((uint32_t)(v.w + 1) << 24);
            }
        }
    }
    __syncthreads();

    if (tid < 64) {
        // ---------------- phase A: wave 0, quad-split, 16 elements ----------------
        const int e = tid >> 2;    // element within block
        const int d = tid & 3;     // edge index this lane handles

        uint64_t L = (((uint64_t)1 << NN) - 1) & ~(uint64_t)3;  // lnf: 0,1 found
        uint64_t V = (((uint64_t)1 << NN) - 1) & ~(uint64_t)1;  // nnv: 0 visited
        uint64_t M = 2;               // found & not visited = {1}
        int visiting = 1, nr = 0;
        uint32_t w = eds[e][0];       // prefetched row of node 1

        #pragma unroll 1
        for (int it = 0; it < A; ++it) {
            const int n0 = w & 0xff, n1 = (w >> 8) & 0xff, n2 = (w >> 16) & 0xff, n3 = w >> 24;
            const uint64_t bu = ((uint64_t)1 << n0) | ((uint64_t)1 << n1)
                              | ((uint64_t)1 << n2) | ((uint64_t)1 << n3);
            const int myn = (w >> (8 * d)) & 0xff;
            const uint64_t bm = (uint64_t)1 << myn;
            // --- next-visit precompute + prefetch (overlaps bookkeeping) ---
            const uint64_t visbit = (uint64_t)1 << visiting;
            const uint64_t Mn = (M | (V & bu)) & ~visbit;   // next found&!visited set
            const bool dn = (Mn == 0);
            const uint64_t Msafe = dn ? (uint64_t)2 : Mn;
            const int nv = (int)__builtin_ctzll(Msafe);     // next visiting (dummy 1 if done)
            const uint32_t wn = eds[e][nv - 1];             // prefetch next edge row
            // --- bookkeeping with OLD L,V ---
            const bool dup = ((d > 0) & (myn == n0)) | ((d > 1) & (myn == n1)) | ((d > 2) & (myn == n2));
            const bool fa  = ((L & bm) == 0) | dup;         // found at my edge's turn
            const bool cf  = fa & ((V & bm) != 0) & (myn != 0);   // cycle edge
            const uint64_t Bc = __ballot(cf);               // all 4 lanes of each quad
            const uint32_t qb = (uint32_t)(Bc >> (tid & 60)) & 0xfu;  // my quad's bits
            const int slot = nr + __builtin_popcount(qb & ((1u << d) - 1));
            nr += __builtin_popcount(qb);
            // exec-guarded stores: few active lanes
            if (!fa) comb[e][myn] = (uint16_t)visiting;     // Tree set-once
            if (cf && slot < NN)
                comb[e][64 + slot] = (uint16_t)(visiting | (myn << 8));  // ring push
            L &= ~bu;
            V &= ~visbit;
            M = Mn; visiting = nv;
            w = dn ? 0u : wn;   // done lanes idle harmlessly
            if (__ballot(!dn) == 0) break;
        }
    } else {
        // ---------- waves 1-7: -1 fill of the block's rings region ----------
        // 16 elements x 16 rows x 50 words = 12800 words = 3200 int4 (aligned).
        int4* rbase = (int4*)(out + (size_t)BATCH * NN * 3 + (size_t)bbase * (MAXR * A));
        const int4 m1 = make_int4(-1, -1, -1, -1);
        const int idx = tid - 64;   // 0..447
        #pragma unroll
        for (int k = 0; k < 8; ++k) {
            const int f = k * 448 + idx;
            if (f < 3200) rbase[f] = m1;
        }
    }
    __syncthreads();   // full vmcnt drain before barrier -> fills committed

    // ---------------- phase B: 8 waves x 2 elements, active rows only ----------------
    const int lane  = tid & 63;
    const int wid   = tid >> 6;
    const int ebase = wid * EPWB;             // this wave's first element in block
    const int gbase = bbase + ebase;          // global element index

    int*  otree = out;                                   // (B,51)
    int2* oridx = (int2*)(out + (size_t)BATCH * NN);     // (B,51) of int2

    uint64_t MkE[EPWB];
    int gE[EPWB], r01E[EPWB];
    #pragma unroll
    for (int j = 0; j < EPWB; ++j) {
        const int ew = ebase + j;
        const int b  = gbase + j;
        const int f = (lane < NN) ? (int)comb[ew][lane] : 0;
        const uint32_t pv = (lane < NN) ? (uint32_t)comb[ew][64 + lane] : 0;
        MkE[j] = ((uint64_t)1 << lane) | ((uint64_t)1 << f);
        gE[j]  = f;
        r01E[j] = (int)pv;                               // slot lane: r0 | r1<<8
        if (lane < NN) {
            otree[(size_t)b * NN + lane] = f;
            oridx[(size_t)b * NN + lane] = make_int2((int)(pv & 0xff), (int)(pv >> 8));
        }
    }
    // ancestor-mask doubling: issue all bpermutes of a step, then combine
    #pragma unroll
    for (int j6 = 0; j6 < 6; ++j6) {
        int lo4[EPWB], hi4[EPWB], gg4[EPWB];
        #pragma unroll
        for (int j = 0; j < EPWB; ++j) {
            const int ad = gE[j] << 2;
            lo4[j] = __builtin_amdgcn_ds_bpermute(ad, (int)(uint32_t)MkE[j]);
            hi4[j] = __builtin_amdgcn_ds_bpermute(ad, (int)(MkE[j] >> 32));
            gg4[j] = (j6 < 5) ? __builtin_amdgcn_ds_bpermute(ad, gE[j]) : gE[j];
        }
        #pragma unroll
        for (int j = 0; j < EPWB; ++j) {
            MkE[j] |= ((uint64_t)(uint32_t)hi4[j] << 32) | (uint32_t)lo4[j];
            gE[j]   = gg4[j];
        }
    }
    // slot prep: issue all bpermutes, then combine
    int depE[EPWB], nactE[EPWB], packE[EPWB];
    int s0loE[EPWB], s0hiE[EPWB], s1loE[EPWB], s1hiE[EPWB];
    {
        int t0l[EPWB], t0h[EPWB], t1l[EPWB], t1h[EPWB];
        #pragma unroll
        for (int j = 0; j < EPWB; ++j) {
            const int Mlo = (int)(uint32_t)MkE[j], Mhi = (int)(MkE[j] >> 32);
            const int a0 = (r01E[j] & 0xff) << 2, a1 = ((r01E[j] >> 8) & 0xff) << 2;
            t0l[j] = __builtin_amdgcn_ds_bpermute(a0, Mlo);
            t0h[j] = __builtin_amdgcn_ds_bpermute(a0, Mhi);
            t1l[j] = __builtin_amdgcn_ds_bpermute(a1, Mlo);
            t1h[j] = __builtin_amdgcn_ds_bpermute(a1, Mhi);
        }
        #pragma unroll
        for (int j = 0; j < EPWB; ++j) {
            const uint64_t set0 = ((uint64_t)(uint32_t)t0h[j] << 32) | (uint32_t)t0l[j];
            const uint64_t set1 = ((uint64_t)(uint32_t)t1h[j] << 32) | (uint32_t)t1l[j];
            depE[j] = __builtin_popcountll(MkE[j]) - 1;
            const int dm  = __builtin_popcountll(set0 & set1) - 1;  // LCA depth
            const int ds0 = __builtin_popcountll(set0) - 1;
            const int ds1 = __builtin_popcountll(set1) - 1;
            const int r0  = r01E[j] & 0xff;
            s0loE[j] = (int)(uint32_t)set0;  s0hiE[j] = (int)(set0 >> 32);
            s1loE[j] = (int)(uint32_t)set1;  s1hiE[j] = (int)(set1 >> 32);
            packE[j] = dm | (ds0 << 8) | (ds1 << 16) | (r0 << 24);
            nactE[j] = __popcll(__ballot((lane < MAXR) && (r0 != 0)));
        }
    }

    // row emission, 4 rows per iteration (independent ds_permutes overlap)
    #pragma unroll
    for (int j = 0; j < EPWB; ++j) {
        const int b = gbase + j;
        int* orings = out + (size_t)BATCH * NN * 3 + (size_t)b * (MAXR * A);
        const int nact = nactE[j];
        const int dep  = depE[j];

        int i = 0;
        for (; i + 3 < nact; i += 4) {
            int p0,t0,u0,v0, p1,t1,u1,v1, p2,t2,u2,v2, p3,t3,u3,v3;
            prep_row(lane, dep, s0loE[j], s0hiE[j], s1loE[j], s1hiE[j], packE[j], i+0, p0,t0,u0,v0);
            prep_row(lane, dep, s0loE[j], s0hiE[j], s1loE[j], s1hiE[j], packE[j], i+1, p1,t1,u1,v1);
            prep_row(lane, dep, s0loE[j], s0hiE[j], s1loE[j], s1hiE[j], packE[j], i+2, p2,t2,u2,v2);
            prep_row(lane, dep, s0loE[j], s0hiE[j], s1loE[j], s1hiE[j], packE[j], i+3, p3,t3,u3,v3);
            const int m0 = __builtin_amdgcn_ds_permute(p0 << 2, lane);
            const int m1 = __builtin_amdgcn_ds_permute(p1 << 2, lane);
            const int m2 = __builtin_amdgcn_ds_permute(p2 << 2, lane);
            const int m3 = __builtin_amdgcn_ds_permute(p3 << 2, lane);
            const int r0v = (lane == t0 + 1) ? v0 : (lane <= u0 ? m0 : 0);
            const int r1v = (lane == t1 + 1) ? v1 : (lane <= u1 ? m1 : 0);
            const int r2v = (lane == t2 + 1) ? v2 : (lane <= u2 ? m2 : 0);
            const int r3v = (lane == t3 + 1) ? v3 : (lane <= u3 ? m3 : 0);
            if (lane < A) {
                orings[(i + 0) * A + lane] = r0v - 1;
                orings[(i + 1) * A + lane] = r1v - 1;
                orings[(i + 2) * A + lane] = r2v - 1;
                orings[(i + 3) * A + lane] = r3v - 1;
            }
        }
        for (; i < nact; ++i) {
            int p0, t0, u0, v0;
            prep_row(lane, dep, s0loE[j], s0hiE[j], s1loE[j], s1hiE[j], packE[j], i, p0,t0,u0,v0);
            const int m0 = __builtin_amdgcn_ds_permute(p0 << 2, lane);
            const int r0v = (lane == t0 + 1) ? v0 : (lane <= u0 ? m0 : 0);
            if (lane < A) orings[i * A + lane] = r0v - 1;
        }
        // tail rows already -1 from the fill-during-A phase
    }
}

extern "C" void kernel_launch(void* const* d_in, const int* in_sizes, int n_in,
                              void* d_out, int out_size, void* d_ws, size_t ws_size,
                              hipStream_t stream) {
    const int* edge = (const int*)d_in[0];
    int* out = (int*)d_out;
    hipLaunchKernelGGL(fused_kernel, dim3(BATCH / EPB), dim3(WPB * 64), 0, stream,
                       edge, out);
}